// Round 4
// baseline (645.907 us; speedup 1.0000x reference)
//
#include <hip/hip_runtime.h>

// ---------------------------------------------------------------------------
// DeformableTransformer encoder layer, MI355X (gfx950).
// R6 (2nd resubmit; two GPUAcquisitionTimeouts — never measured):
// deform_sample rewritten lane-per-head (8 lanes/token, 32 ch/lane):
//   - removes 4x-redundant weight/address/softmax math (was 86% VALUBusy)
//   - algebraic fdiv removal: x = rx*W + ox - 0.5 (no v_div_* sequence)
//   - __expf softmax, vectorized logit/offset loads, imm-offset corner loads
// Carried: fused softmax (R5); gemm128 dbuf GLDS + coalesced epilogue (R4).
// ---------------------------------------------------------------------------

#define BLTOK 52500   // B*L tokens
#define MP    52608   // BLTOK padded to multiple of 128
#define LSP   13125   // L (spatial length per batch)

using short8  = __attribute__((ext_vector_type(8))) short;
using ushort8v= __attribute__((ext_vector_type(8))) unsigned short;
using f32x4   = __attribute__((ext_vector_type(4))) float;
using fl2     = __attribute__((ext_vector_type(2))) float;

__device__ __forceinline__ ushort f2b(float f) {
  union { float f; unsigned u; } x; x.f = f;
  unsigned r = (x.u + 0x7fffu + ((x.u >> 16) & 1u)) >> 16;
  return (ushort)r;
}
__device__ __forceinline__ float b2f(ushort h) {
  union { unsigned u; float f; } x; x.u = ((unsigned)h) << 16;
  return x.f;
}
__device__ __forceinline__ float blo(uint u) {   // low bf16 of packed uint
  union { unsigned u; float f; } x; x.u = u << 16;
  return x.f;
}
__device__ __forceinline__ float bhi(uint u) {   // high bf16 of packed uint
  union { unsigned u; float f; } x; x.u = u & 0xffff0000u;
  return x.f;
}

#define GLDS16(gp, lp) __builtin_amdgcn_global_load_lds( \
    (const __attribute__((address_space(1))) void*)(gp), \
    (__attribute__((address_space(3))) void*)(lp), 16, 0, 0)

// ---------------- weight prep: transpose to N x K, convert bf16 -------------
__global__ __launch_bounds__(256) void prep_weights(
    const float* __restrict__ Wv, const float* __restrict__ Woff,
    const float* __restrict__ Wattn, const float* __restrict__ Wout,
    const float* __restrict__ Wff1, const float* __restrict__ Wff2,
    const float* __restrict__ boff, const float* __restrict__ battn,
    ushort* __restrict__ wv_t, ushort* __restrict__ wcat_t,
    ushort* __restrict__ wout_t, ushort* __restrict__ wff1_t,
    ushort* __restrict__ wff2_t, float* __restrict__ bcat)
{
  int i = blockIdx.x * 256 + threadIdx.x;
  if (i < 65536) {
    int n = i >> 8, k = i & 255;
    wv_t[i] = f2b(Wv[k * 256 + n]);
    return;
  }
  int j = i - 65536;
  if (j < 98304) {                       // 384 rows (320.. zero)
    int n = j >> 8, k = j & 255;
    float v = (n < 192) ? Woff[k * 192 + n]
            : (n < 288) ? Wattn[k * 96 + (n - 192)] : 0.f;
    wcat_t[j] = f2b(v);
    return;
  }
  j -= 98304;
  if (j < 65536) {
    int n = j >> 8, k = j & 255;
    wout_t[j] = f2b(Wout[k * 256 + n]);
    return;
  }
  j -= 65536;
  if (j < 262144) {
    int n = j >> 8, k = j & 255;
    wff1_t[j] = f2b(Wff1[k * 1024 + n]);
    return;
  }
  j -= 262144;
  if (j < 262144) {
    int n = j >> 10, k = j & 1023;
    wff2_t[j] = f2b(Wff2[k * 256 + n]);
    return;
  }
  j -= 262144;
  if (j < 384) bcat[j] = (j < 192) ? boff[j] : (j < 288) ? battn[j - 192] : 0.f;
}

// ---------------- activation prep: bf16 src and q=src+pos, zero pad rows ----
__global__ __launch_bounds__(256) void prep_act(
    const float* __restrict__ src, const float* __restrict__ pos,
    ushort* __restrict__ src_bf, ushort* __restrict__ q_bf)
{
  const size_t e = ((size_t)blockIdx.x * 256 + threadIdx.x) * 4;
  if (e >= (size_t)MP * 256) return;
  ushort4 sb, qb;
  if (e < (size_t)BLTOK * 256) {
    const float4 s = *(const float4*)(src + e);
    const float4 p = *(const float4*)(pos + e);
    sb.x = f2b(s.x); sb.y = f2b(s.y); sb.z = f2b(s.z); sb.w = f2b(s.w);
    qb.x = f2b(s.x + p.x); qb.y = f2b(s.y + p.y);
    qb.z = f2b(s.z + p.z); qb.w = f2b(s.w + p.w);
  } else {
    sb.x = sb.y = sb.z = sb.w = 0;
    qb.x = qb.y = qb.z = qb.w = 0;
  }
  *(ushort4*)(src_bf + e) = sb;
  *(ushort4*)(q_bf + e) = qb;
}

// ---------------- GEMM 128x128, dbuf GLDS staging, coalesced epilogue -------
// grid = (Ntiles, Mtiles): consecutive blocks share the A m-tile (L2 reuse).
// EPI: 0 = bias; 1 = + addf(f32); 2 = relu; 3 = + addb(bf16)
template <int EPI>
__global__ __launch_bounds__(256) void gemm128(
    const ushort* __restrict__ A, const ushort* __restrict__ Bt,
    const float* __restrict__ bias, const float* __restrict__ addf,
    const ushort* __restrict__ addb, ushort* __restrict__ C,
    int Mact, int Nact, int Nstr, int K)
{
  __shared__ __align__(16) ushort sm[16384];     // 32 KB
  ushort* As = sm;                               // [2][4096]
  ushort* Bs = sm + 8192;                        // [2][4096]
  float*  epf = (float*)sm;                      // epilogue: 64 x 128 f32
  const int tid = threadIdx.x;
  const int wave = tid >> 6, lane = tid & 63;
  const int n0 = blockIdx.x * 128, m0 = blockIdx.y * 128;
  const int srow = lane >> 2, skc = (lane & 3) * 8;
  const ushort* Ag = A + (size_t)(m0 + wave * 32 + srow) * K + skc;
  const ushort* Bg = Bt + (size_t)(n0 + wave * 32 + srow) * K + skc;
  const int quad = lane >> 4, l16 = lane & 15;
  const int wm = (wave & 1) * 64, wn = (wave >> 1) * 64;
  f32x4 acc[4][4] = {};

#define STAGE(buf, kk) { \
    ushort* la = As + (buf) * 4096 + wave * 1024; \
    ushort* lb = Bs + (buf) * 4096 + wave * 1024; \
    GLDS16(Ag + (kk), la); \
    GLDS16(Ag + (kk) + 16 * K, la + 512); \
    GLDS16(Bg + (kk), lb); \
    GLDS16(Bg + (kk) + 16 * K, lb + 512); }

  STAGE(0, 0);
  int cur = 0;
  for (int k0 = 0; k0 < K; k0 += 32) {
    __syncthreads();                      // drains staging of `cur`
    if (k0 + 32 < K) STAGE(cur ^ 1, k0 + 32);   // prefetch overlaps compute
    const ushort* Ab = As + cur * 4096;
    const ushort* Bb = Bs + cur * 4096;
    short8 af[4], bf[4];
#pragma unroll
    for (int i = 0; i < 4; i++)
      af[i] = *(const short8*)(&Ab[(wm + i * 16 + l16) * 32 + quad * 8]);
#pragma unroll
    for (int j = 0; j < 4; j++)
      bf[j] = *(const short8*)(&Bb[(wn + j * 16 + l16) * 32 + quad * 8]);
#pragma unroll
    for (int i = 0; i < 4; i++)
#pragma unroll
      for (int j = 0; j < 4; j++)
        acc[i][j] = __builtin_amdgcn_mfma_f32_16x16x32_bf16(af[i], bf[j],
                                                            acc[i][j], 0, 0, 0);
    cur ^= 1;
  }
#undef STAGE

  // coalesced epilogue: two 64-row rounds through f32 LDS
  for (int half = 0; half < 2; half++) {
    __syncthreads();
    if ((wave & 1) == half) {
      // C/D: col = l16, row = quad*4 + r  [m89/m91]
#pragma unroll
      for (int i = 0; i < 4; i++)
#pragma unroll
        for (int j = 0; j < 4; j++)
#pragma unroll
          for (int r = 0; r < 4; r++)
            epf[(i * 16 + quad * 4 + r) * 128 + wn + j * 16 + l16] = acc[i][j][r];
    }
    __syncthreads();
    const int gm0 = m0 + half * 64;
#pragma unroll
    for (int g = 0; g < 4; g++) {
      const int lrow = g * 16 + (tid >> 4);
      const int col0 = (tid & 15) * 8;
      const int grow = gm0 + lrow;
      const int gcol = n0 + col0;
      if (grow < Mact && gcol < Nact) {
        float v[8];
#pragma unroll
        for (int c = 0; c < 8; c++) v[c] = epf[lrow * 128 + col0 + c] + bias[gcol + c];
        const size_t idx = (size_t)grow * Nstr + gcol;
        if (EPI == 1) {
          const float4 a0 = *(const float4*)(addf + idx);
          const float4 a1 = *(const float4*)(addf + idx + 4);
          v[0] += a0.x; v[1] += a0.y; v[2] += a0.z; v[3] += a0.w;
          v[4] += a1.x; v[5] += a1.y; v[6] += a1.z; v[7] += a1.w;
        }
        if (EPI == 2) {
#pragma unroll
          for (int c = 0; c < 8; c++) v[c] = fmaxf(v[c], 0.f);
        }
        if (EPI == 3) {
          const ushort8v ab = *(const ushort8v*)(addb + idx);
#pragma unroll
          for (int c = 0; c < 8; c++) v[c] += b2f(ab[c]);
        }
        ushort8v o;
#pragma unroll
        for (int c = 0; c < 8; c++) o[c] = f2b(v[c]);
        *(ushort8v*)(C + idx) = o;
      }
    }
  }
}

// ---------------- MS-deform-attn bilinear sampling core ---------------------
// R6: 8 lanes/token, lane owns head h (all 32 channels). In-register softmax
// over the head's 12 logits; no redundant per-head math; no f32 divides
// (x = rx*W + ox - 0.5 exactly equals ((rx + ox/W)*W - 0.5)).
__global__ __launch_bounds__(256) void deform_sample(
    const ushort* __restrict__ value, const ushort* __restrict__ oa_all,
    const float* __restrict__ refp, ushort* __restrict__ outb)
{
  const int tid = threadIdx.x;
  const int tok = blockIdx.x * 32 + (tid >> 3);
  if (tok >= BLTOK) return;
  const int b = tok / LSP;
  const int h = tid & 7;
  const ushort* oa = oa_all + (uint)tok * 320u;
  const float* rp = refp + (uint)tok * 6u;
  const uint base = (uint)b * (LSP * 256u) + (uint)(h * 32);

  // --- sampling offsets: 12 packed (x,y) bf16 pairs, 48B 16-aligned ---
  const uint4 oq0 = *(const uint4*)(oa + h * 24);
  const uint4 oq1 = *(const uint4*)(oa + h * 24 + 8);
  const uint4 oq2 = *(const uint4*)(oa + h * 24 + 16);
  const uint oxy[12] = {oq0.x, oq0.y, oq0.z, oq0.w,
                        oq1.x, oq1.y, oq1.z, oq1.w,
                        oq2.x, oq2.y, oq2.z, oq2.w};

  // --- attn logits: 12 bf16, 24B 8-aligned; softmax in-register ---
  const ushort* lgp = oa + 192 + h * 12;
  const uint2 lq0 = *(const uint2*)(lgp);
  const uint2 lq1 = *(const uint2*)(lgp + 4);
  const uint2 lq2 = *(const uint2*)(lgp + 8);
  float w[12] = {blo(lq0.x), bhi(lq0.x), blo(lq0.y), bhi(lq0.y),
                 blo(lq1.x), bhi(lq1.x), blo(lq1.y), bhi(lq1.y),
                 blo(lq2.x), bhi(lq2.x), blo(lq2.y), bhi(lq2.y)};
  float mx = -1e30f;
#pragma unroll
  for (int i = 0; i < 12; i++) mx = fmaxf(mx, w[i]);
  float s = 0.f;
#pragma unroll
  for (int i = 0; i < 12; i++) { w[i] = __expf(w[i] - mx); s += w[i]; }
  const float inv = __builtin_amdgcn_rcpf(s);

  const int Wl[3] = {100, 50, 25};
  const int Stl[3] = {0, 10000, 12500};
  fl2 acc[16] = {};
#pragma unroll
  for (int lid = 0; lid < 3; lid++) {
    const int W = Wl[lid], st = Stl[lid];   // square levels: H == W
    const float Wf = (float)W;
    const float rxw = rp[lid * 2] * Wf - 0.5f;
    const float ryw = rp[lid * 2 + 1] * Wf - 0.5f;
#pragma unroll
    for (int p = 0; p < 4; p++) {
      const uint o = oxy[lid * 4 + p];
      const float aw = w[lid * 4 + p] * inv;
      const float x = rxw + blo(o);      // == (rx + ox/W)*W - 0.5
      const float y = ryw + bhi(o);
      const float x0f = floorf(x), y0f = floorf(y);
      const float wx1 = x - x0f, wy1 = y - y0f;
      const float wx0 = 1.f - wx1, wy0 = 1.f - wy1;
      const int ix0 = (int)x0f, iy0 = (int)y0f;
      const bool x0v = (ix0 >= 0) & (ix0 < W);
      const bool x1v = (ix0 + 1 >= 0) & (ix0 + 1 < W);
      const bool y0v = (iy0 >= 0) & (iy0 < W);
      const bool y1v = (iy0 + 1 >= 0) & (iy0 + 1 < W);
      const float ay0 = aw * wy0, ay1 = aw * wy1;
      const float w00 = (x0v & y0v) ? ay0 * wx0 : 0.f;
      const float w10 = (x1v & y0v) ? ay0 * wx1 : 0.f;
      const float w01 = (x0v & y1v) ? ay1 * wx0 : 0.f;
      const float w11 = (x1v & y1v) ? ay1 * wx1 : 0.f;
      const int ix0c = min(max(ix0, 0), W - 1);
      const int ix1c = min(max(ix0 + 1, 0), W - 1);
      const int iy0c = min(max(iy0, 0), W - 1);
      const int iy1c = min(max(iy0 + 1, 0), W - 1);
      const ushort* p00 = value + base + (uint)(st + iy0c * W + ix0c) * 256u;
      const ushort* p10 = value + base + (uint)(st + iy0c * W + ix1c) * 256u;
      const ushort* p01 = value + base + (uint)(st + iy1c * W + ix0c) * 256u;
      const ushort* p11 = value + base + (uint)(st + iy1c * W + ix1c) * 256u;
      const fl2 w00v = {w00, w00}, w10v = {w10, w10};
      const fl2 w01v = {w01, w01}, w11v = {w11, w11};
#pragma unroll
      for (int j = 0; j < 4; j++) {       // 4 x dwordx4 per corner, imm offsets
        const uint4 q00 = *(const uint4*)(p00 + j * 8);
        const uint4 q10 = *(const uint4*)(p10 + j * 8);
        const uint4 q01 = *(const uint4*)(p01 + j * 8);
        const uint4 q11 = *(const uint4*)(p11 + j * 8);
        const uint* u00 = (const uint*)&q00;
        const uint* u10 = (const uint*)&q10;
        const uint* u01 = (const uint*)&q01;
        const uint* u11 = (const uint*)&q11;
#pragma unroll
        for (int e = 0; e < 4; e++) {
          const fl2 v00 = {blo(u00[e]), bhi(u00[e])};
          const fl2 v10 = {blo(u10[e]), bhi(u10[e])};
          const fl2 v01 = {blo(u01[e]), bhi(u01[e])};
          const fl2 v11 = {blo(u11[e]), bhi(u11[e])};
          acc[j * 4 + e] += w00v * v00 + w10v * v10 + w01v * v01 + w11v * v11;
        }
      }
    }
  }
  ushort* op = outb + (uint)tok * 256u + (uint)(h * 32);
#pragma unroll
  for (int j = 0; j < 4; j++) {
    ushort8v o;
#pragma unroll
    for (int e = 0; e < 4; e++) {
      o[e * 2]     = f2b(acc[j * 4 + e].x);
      o[e * 2 + 1] = f2b(acc[j * 4 + e].y);
    }
    *(ushort8v*)(op + j * 8) = o;
  }
}

// ---------------- LayerNorm over 256 (wave per row, 4 rows/block) -----------
template <int OUTF>
__global__ __launch_bounds__(256) void ln256(
    const ushort* __restrict__ in, const float* __restrict__ gg,
    const float* __restrict__ bb, ushort* __restrict__ outb,
    float* __restrict__ outf, int rows)
{
  const int wave = threadIdx.x >> 6, lane = threadIdx.x & 63;
  const int r = blockIdx.x * 4 + wave;
  if (r >= rows) return;
  const ushort* rowp = in + (size_t)r * 256;
  const ushort4 u = *(const ushort4*)(rowp + lane * 4);
  float v[4] = {b2f(u.x), b2f(u.y), b2f(u.z), b2f(u.w)};
  float s = v[0] + v[1] + v[2] + v[3];
  float s2 = v[0] * v[0] + v[1] * v[1] + v[2] * v[2] + v[3] * v[3];
#pragma unroll
  for (int o = 32; o > 0; o >>= 1) {
    s += __shfl_xor(s, o);
    s2 += __shfl_xor(s2, o);
  }
  const float mean = s * (1.f / 256.f);
  const float var = s2 * (1.f / 256.f) - mean * mean;
  const float rstd = rsqrtf(var + 1e-5f);
#pragma unroll
  for (int j = 0; j < 4; j++) {
    const int col = lane * 4 + j;
    const float o = (v[j] - mean) * rstd * gg[col] + bb[col];
    if (OUTF) outf[(size_t)r * 256 + col] = o;
    else outb[(size_t)r * 256 + col] = f2b(o);
  }
}

// ---------------------------------------------------------------------------
extern "C" void kernel_launch(void* const* d_in, const int* in_sizes, int n_in,
                              void* d_out, int out_size, void* d_ws, size_t ws_size,
                              hipStream_t stream)
{
  const float* src   = (const float*)d_in[0];
  const float* pos   = (const float*)d_in[1];
  const float* refp  = (const float*)d_in[2];
  const float* Wv    = (const float*)d_in[3];
  const float* bv    = (const float*)d_in[4];
  const float* Woff  = (const float*)d_in[5];
  const float* boff  = (const float*)d_in[6];
  const float* Wattn = (const float*)d_in[7];
  const float* battn = (const float*)d_in[8];
  const float* Wout  = (const float*)d_in[9];
  const float* bout  = (const float*)d_in[10];
  const float* g1    = (const float*)d_in[11];
  const float* b1    = (const float*)d_in[12];
  const float* Wff1  = (const float*)d_in[13];
  const float* bff1  = (const float*)d_in[14];
  const float* Wff2  = (const float*)d_in[15];
  const float* bff2  = (const float*)d_in[16];
  const float* g2    = (const float*)d_in[17];
  const float* b2    = (const float*)d_in[18];
  float* out = (float*)d_out;
  char* ws = (char*)d_ws;

  // workspace (bytes). wv_t / wout_t overlaid on A5 tail (dead before G4
  // writes h there); attn_out uses A5's head (dead until G4).
  ushort* wcat_t = (ushort*)(ws + 0);            //   196608 (384 x 256)
  ushort* wff1_t = (ushort*)(ws + 196608);       //   524288
  ushort* wff2_t = (ushort*)(ws + 720896);       //   524288
  float*  bcat   = (float*)(ws + 1245184);       //     1536
  ushort* A1 = (ushort*)(ws + 1246720);          // src_bf (lives to G3)
  ushort* A2 = (ushort*)(ws + 28182016);         // q_bf -> x_bf
  ushort* A3 = (ushort*)(ws + 55117312);         // value -> y_bf
  ushort* A4 = (ushort*)(ws + 81997312);         // offattn(320) -> xpre(256)
  ushort* A5 = (ushort*)(ws + 115597312);        // attn_out (head) -> h (MPx1024)
  ushort* wout_t = (ushort*)(ws + 223076352);    //   131072 (A5 tail)
  ushort* wv_t   = (ushort*)(ws + 223207424);    //   131072 (A5 tail)
  // end: 223338496

  prep_weights<<<2946, 256, 0, stream>>>(Wv, Woff, Wattn, Wout, Wff1, Wff2,
                                         boff, battn,
                                         wv_t, wcat_t, wout_t, wff1_t, wff2_t, bcat);
  prep_act<<<MP / 4, 256, 0, stream>>>(src, pos, A1, A2);
  // G1: value = src @ Wv + bv
  gemm128<0><<<dim3(2, MP / 128), 256, 0, stream>>>(A1, wv_t, bv, nullptr, nullptr,
                                                    A3, BLTOK, 256, 256, 256);
  // G2: offattn = q @ Wcat + bcat  (N=320, tiles to 384)
  gemm128<0><<<dim3(3, MP / 128), 256, 0, stream>>>(A2, wcat_t, bcat, nullptr, nullptr,
                                                    A4, BLTOK, 320, 320, 256);
  // attn_out -> A5 head  (softmax fused in-register, lane-per-head)
  deform_sample<<<(BLTOK + 31) / 32, 256, 0, stream>>>(A3, A4, refp, A5);
  // G3: xpre = src_bf + attn_out @ Wout + bout  (bf16 residual from A1)
  gemm128<3><<<dim3(2, MP / 128), 256, 0, stream>>>(A5, wout_t, bout, nullptr, A1,
                                                    A4, BLTOK, 256, 256, 256);
  ln256<0><<<BLTOK / 4, 256, 0, stream>>>(A4, g1, b1, A2, nullptr, BLTOK);
  // G4: h = relu(x @ Wff1 + bff1) — store pad rows too (A2 pads are zero)
  gemm128<2><<<dim3(8, MP / 128), 256, 0, stream>>>(A2, wff1_t, bff1, nullptr, nullptr,
                                                    A5, MP, 1024, 1024, 256);
  // G5: y = x + h @ Wff2 + bff2
  gemm128<3><<<dim3(2, MP / 128), 256, 0, stream>>>(A5, wff2_t, bff2, nullptr, A2,
                                                    A3, BLTOK, 256, 256, 1024);
  ln256<1><<<BLTOK / 4, 256, 0, stream>>>(A3, g2, b2, nullptr, out, BLTOK);
}

// Round 5
// 468.864 us; speedup vs baseline: 1.3776x; 1.3776x over previous
//
#include <hip/hip_runtime.h>

// ---------------------------------------------------------------------------
// DeformableTransformer encoder layer, MI355X (gfx950).
// R7: deform_sample = R5's 32-lane/token layout (measured 100us, good
// coalescing + 26K waves) + layout-independent VALU cuts from R6:
//   - algebraic fdiv removal: x = rx*W + ox - 0.5 (no v_div_* sequence)
//   - __expf + rcp softmax (was libm expf)
//   - vectorized offset (3x uint4) and logit (3x uint2) loads
// R6 post-mortem: 8-lane/token layout was latency-bound (VALU 13%, HBM 20%,
// occ 29%, FETCH 2x from scatter) — reverted.
// Carried: fused softmax (R5); gemm128 dbuf GLDS + coalesced epilogue (R4).
// ---------------------------------------------------------------------------

#define BLTOK 52500   // B*L tokens
#define MP    52608   // BLTOK padded to multiple of 128
#define LSP   13125   // L (spatial length per batch)

using short8  = __attribute__((ext_vector_type(8))) short;
using ushort8v= __attribute__((ext_vector_type(8))) unsigned short;
using f32x4   = __attribute__((ext_vector_type(4))) float;
using fl2     = __attribute__((ext_vector_type(2))) float;

__device__ __forceinline__ ushort f2b(float f) {
  union { float f; unsigned u; } x; x.f = f;
  unsigned r = (x.u + 0x7fffu + ((x.u >> 16) & 1u)) >> 16;
  return (ushort)r;
}
__device__ __forceinline__ float b2f(ushort h) {
  union { unsigned u; float f; } x; x.u = ((unsigned)h) << 16;
  return x.f;
}
__device__ __forceinline__ float blo(uint u) {   // low bf16 of packed uint
  union { unsigned u; float f; } x; x.u = u << 16;
  return x.f;
}
__device__ __forceinline__ float bhi(uint u) {   // high bf16 of packed uint
  union { unsigned u; float f; } x; x.u = u & 0xffff0000u;
  return x.f;
}

#define GLDS16(gp, lp) __builtin_amdgcn_global_load_lds( \
    (const __attribute__((address_space(1))) void*)(gp), \
    (__attribute__((address_space(3))) void*)(lp), 16, 0, 0)

// ---------------- weight prep: transpose to N x K, convert bf16 -------------
__global__ __launch_bounds__(256) void prep_weights(
    const float* __restrict__ Wv, const float* __restrict__ Woff,
    const float* __restrict__ Wattn, const float* __restrict__ Wout,
    const float* __restrict__ Wff1, const float* __restrict__ Wff2,
    const float* __restrict__ boff, const float* __restrict__ battn,
    ushort* __restrict__ wv_t, ushort* __restrict__ wcat_t,
    ushort* __restrict__ wout_t, ushort* __restrict__ wff1_t,
    ushort* __restrict__ wff2_t, float* __restrict__ bcat)
{
  int i = blockIdx.x * 256 + threadIdx.x;
  if (i < 65536) {
    int n = i >> 8, k = i & 255;
    wv_t[i] = f2b(Wv[k * 256 + n]);
    return;
  }
  int j = i - 65536;
  if (j < 98304) {                       // 384 rows (320.. zero)
    int n = j >> 8, k = j & 255;
    float v = (n < 192) ? Woff[k * 192 + n]
            : (n < 288) ? Wattn[k * 96 + (n - 192)] : 0.f;
    wcat_t[j] = f2b(v);
    return;
  }
  j -= 98304;
  if (j < 65536) {
    int n = j >> 8, k = j & 255;
    wout_t[j] = f2b(Wout[k * 256 + n]);
    return;
  }
  j -= 65536;
  if (j < 262144) {
    int n = j >> 8, k = j & 255;
    wff1_t[j] = f2b(Wff1[k * 1024 + n]);
    return;
  }
  j -= 262144;
  if (j < 262144) {
    int n = j >> 10, k = j & 1023;
    wff2_t[j] = f2b(Wff2[k * 256 + n]);
    return;
  }
  j -= 262144;
  if (j < 384) bcat[j] = (j < 192) ? boff[j] : (j < 288) ? battn[j - 192] : 0.f;
}

// ---------------- activation prep: bf16 src and q=src+pos, zero pad rows ----
__global__ __launch_bounds__(256) void prep_act(
    const float* __restrict__ src, const float* __restrict__ pos,
    ushort* __restrict__ src_bf, ushort* __restrict__ q_bf)
{
  const size_t e = ((size_t)blockIdx.x * 256 + threadIdx.x) * 4;
  if (e >= (size_t)MP * 256) return;
  ushort4 sb, qb;
  if (e < (size_t)BLTOK * 256) {
    const float4 s = *(const float4*)(src + e);
    const float4 p = *(const float4*)(pos + e);
    sb.x = f2b(s.x); sb.y = f2b(s.y); sb.z = f2b(s.z); sb.w = f2b(s.w);
    qb.x = f2b(s.x + p.x); qb.y = f2b(s.y + p.y);
    qb.z = f2b(s.z + p.z); qb.w = f2b(s.w + p.w);
  } else {
    sb.x = sb.y = sb.z = sb.w = 0;
    qb.x = qb.y = qb.z = qb.w = 0;
  }
  *(ushort4*)(src_bf + e) = sb;
  *(ushort4*)(q_bf + e) = qb;
}

// ---------------- GEMM 128x128, dbuf GLDS staging, coalesced epilogue -------
// grid = (Ntiles, Mtiles): consecutive blocks share the A m-tile (L2 reuse).
// EPI: 0 = bias; 1 = + addf(f32); 2 = relu; 3 = + addb(bf16)
template <int EPI>
__global__ __launch_bounds__(256) void gemm128(
    const ushort* __restrict__ A, const ushort* __restrict__ Bt,
    const float* __restrict__ bias, const float* __restrict__ addf,
    const ushort* __restrict__ addb, ushort* __restrict__ C,
    int Mact, int Nact, int Nstr, int K)
{
  __shared__ __align__(16) ushort sm[16384];     // 32 KB
  ushort* As = sm;                               // [2][4096]
  ushort* Bs = sm + 8192;                        // [2][4096]
  float*  epf = (float*)sm;                      // epilogue: 64 x 128 f32
  const int tid = threadIdx.x;
  const int wave = tid >> 6, lane = tid & 63;
  const int n0 = blockIdx.x * 128, m0 = blockIdx.y * 128;
  const int srow = lane >> 2, skc = (lane & 3) * 8;
  const ushort* Ag = A + (size_t)(m0 + wave * 32 + srow) * K + skc;
  const ushort* Bg = Bt + (size_t)(n0 + wave * 32 + srow) * K + skc;
  const int quad = lane >> 4, l16 = lane & 15;
  const int wm = (wave & 1) * 64, wn = (wave >> 1) * 64;
  f32x4 acc[4][4] = {};

#define STAGE(buf, kk) { \
    ushort* la = As + (buf) * 4096 + wave * 1024; \
    ushort* lb = Bs + (buf) * 4096 + wave * 1024; \
    GLDS16(Ag + (kk), la); \
    GLDS16(Ag + (kk) + 16 * K, la + 512); \
    GLDS16(Bg + (kk), lb); \
    GLDS16(Bg + (kk) + 16 * K, lb + 512); }

  STAGE(0, 0);
  int cur = 0;
  for (int k0 = 0; k0 < K; k0 += 32) {
    __syncthreads();                      // drains staging of `cur`
    if (k0 + 32 < K) STAGE(cur ^ 1, k0 + 32);   // prefetch overlaps compute
    const ushort* Ab = As + cur * 4096;
    const ushort* Bb = Bs + cur * 4096;
    short8 af[4], bf[4];
#pragma unroll
    for (int i = 0; i < 4; i++)
      af[i] = *(const short8*)(&Ab[(wm + i * 16 + l16) * 32 + quad * 8]);
#pragma unroll
    for (int j = 0; j < 4; j++)
      bf[j] = *(const short8*)(&Bb[(wn + j * 16 + l16) * 32 + quad * 8]);
#pragma unroll
    for (int i = 0; i < 4; i++)
#pragma unroll
      for (int j = 0; j < 4; j++)
        acc[i][j] = __builtin_amdgcn_mfma_f32_16x16x32_bf16(af[i], bf[j],
                                                            acc[i][j], 0, 0, 0);
    cur ^= 1;
  }
#undef STAGE

  // coalesced epilogue: two 64-row rounds through f32 LDS
  for (int half = 0; half < 2; half++) {
    __syncthreads();
    if ((wave & 1) == half) {
      // C/D: col = l16, row = quad*4 + r  [m89/m91]
#pragma unroll
      for (int i = 0; i < 4; i++)
#pragma unroll
        for (int j = 0; j < 4; j++)
#pragma unroll
          for (int r = 0; r < 4; r++)
            epf[(i * 16 + quad * 4 + r) * 128 + wn + j * 16 + l16] = acc[i][j][r];
    }
    __syncthreads();
    const int gm0 = m0 + half * 64;
#pragma unroll
    for (int g = 0; g < 4; g++) {
      const int lrow = g * 16 + (tid >> 4);
      const int col0 = (tid & 15) * 8;
      const int grow = gm0 + lrow;
      const int gcol = n0 + col0;
      if (grow < Mact && gcol < Nact) {
        float v[8];
#pragma unroll
        for (int c = 0; c < 8; c++) v[c] = epf[lrow * 128 + col0 + c] + bias[gcol + c];
        const size_t idx = (size_t)grow * Nstr + gcol;
        if (EPI == 1) {
          const float4 a0 = *(const float4*)(addf + idx);
          const float4 a1 = *(const float4*)(addf + idx + 4);
          v[0] += a0.x; v[1] += a0.y; v[2] += a0.z; v[3] += a0.w;
          v[4] += a1.x; v[5] += a1.y; v[6] += a1.z; v[7] += a1.w;
        }
        if (EPI == 2) {
#pragma unroll
          for (int c = 0; c < 8; c++) v[c] = fmaxf(v[c], 0.f);
        }
        if (EPI == 3) {
          const ushort8v ab = *(const ushort8v*)(addb + idx);
#pragma unroll
          for (int c = 0; c < 8; c++) v[c] += b2f(ab[c]);
        }
        ushort8v o;
#pragma unroll
        for (int c = 0; c < 8; c++) o[c] = f2b(v[c]);
        *(ushort8v*)(C + idx) = o;
      }
    }
  }
}

// ---------------- MS-deform-attn bilinear sampling core ---------------------
// 32 lanes/token: lane l -> head h=l>>2, 8 channels. float2 packed FMAs.
// In-register softmax (fused); __expf + rcp; no f32 divides; vector loads.
__global__ __launch_bounds__(256) void deform_sample(
    const ushort* __restrict__ value, const ushort* __restrict__ oa_all,
    const float* __restrict__ refp, ushort* __restrict__ outb)
{
  const int tid = threadIdx.x;
  const int tok = blockIdx.x * 8 + (tid >> 5);
  if (tok >= BLTOK) return;
  const int b = tok / LSP;
  const int l = tid & 31;
  const int h = l >> 2;
  const ushort* oa = oa_all + (uint)tok * 320u;
  const float* rp = refp + (uint)tok * 6u;
  const uint base = (uint)b * (LSP * 256u) + (uint)(l * 8);

  // --- sampling offsets: 12 packed (x,y) bf16 pairs, 48B 16-aligned ---
  const uint4 oq0 = *(const uint4*)(oa + h * 24);
  const uint4 oq1 = *(const uint4*)(oa + h * 24 + 8);
  const uint4 oq2 = *(const uint4*)(oa + h * 24 + 16);
  const uint oxy[12] = {oq0.x, oq0.y, oq0.z, oq0.w,
                        oq1.x, oq1.y, oq1.z, oq1.w,
                        oq2.x, oq2.y, oq2.z, oq2.w};

  // --- attn logits: 12 bf16, 24B 8-aligned; softmax in-register ---
  const ushort* lgp = oa + 192 + h * 12;
  const uint2 lq0 = *(const uint2*)(lgp);
  const uint2 lq1 = *(const uint2*)(lgp + 4);
  const uint2 lq2 = *(const uint2*)(lgp + 8);
  float w[12] = {blo(lq0.x), bhi(lq0.x), blo(lq0.y), bhi(lq0.y),
                 blo(lq1.x), bhi(lq1.x), blo(lq1.y), bhi(lq1.y),
                 blo(lq2.x), bhi(lq2.x), blo(lq2.y), bhi(lq2.y)};
  float mx = -1e30f;
#pragma unroll
  for (int i = 0; i < 12; i++) mx = fmaxf(mx, w[i]);
  float s = 0.f;
#pragma unroll
  for (int i = 0; i < 12; i++) { w[i] = __expf(w[i] - mx); s += w[i]; }
  const float inv = __builtin_amdgcn_rcpf(s);

  const int Wl[3] = {100, 50, 25};
  const int Stl[3] = {0, 10000, 12500};
  fl2 acc2[4] = {};
#pragma unroll
  for (int lid = 0; lid < 3; lid++) {
    const int W = Wl[lid], st = Stl[lid];   // square levels: H == W
    const float Wf = (float)W;
    const float rxw = rp[lid * 2] * Wf - 0.5f;
    const float ryw = rp[lid * 2 + 1] * Wf - 0.5f;
#pragma unroll
    for (int p = 0; p < 4; p++) {
      const uint o = oxy[lid * 4 + p];
      const float aw = w[lid * 4 + p] * inv;
      const float x = rxw + blo(o);      // == (rx + ox/W)*W - 0.5
      const float y = ryw + bhi(o);
      const float x0f = floorf(x), y0f = floorf(y);
      const float wx1 = x - x0f, wy1 = y - y0f;
      const float wx0 = 1.f - wx1, wy0 = 1.f - wy1;
      const int ix0 = (int)x0f, iy0 = (int)y0f;
      const bool x0v = (ix0 >= 0) & (ix0 < W);
      const bool x1v = (ix0 + 1 >= 0) & (ix0 + 1 < W);
      const bool y0v = (iy0 >= 0) & (iy0 < W);
      const bool y1v = (iy0 + 1 >= 0) & (iy0 + 1 < W);
      const float ay0 = aw * wy0, ay1 = aw * wy1;
      const float w00 = (x0v & y0v) ? ay0 * wx0 : 0.f;
      const float w10 = (x1v & y0v) ? ay0 * wx1 : 0.f;
      const float w01 = (x0v & y1v) ? ay1 * wx0 : 0.f;
      const float w11 = (x1v & y1v) ? ay1 * wx1 : 0.f;
      const int ix0c = min(max(ix0, 0), W - 1);
      const int ix1c = min(max(ix0 + 1, 0), W - 1);
      const int iy0c = min(max(iy0, 0), W - 1);
      const int iy1c = min(max(iy0 + 1, 0), W - 1);
      const uint r00 = (uint)(st + iy0c * W + ix0c) * 256u;
      const uint r10 = (uint)(st + iy0c * W + ix1c) * 256u;
      const uint r01 = (uint)(st + iy1c * W + ix0c) * 256u;
      const uint r11 = (uint)(st + iy1c * W + ix1c) * 256u;
      const uint4 q00 = *(const uint4*)(value + base + r00);
      const uint4 q10 = *(const uint4*)(value + base + r10);
      const uint4 q01 = *(const uint4*)(value + base + r01);
      const uint4 q11 = *(const uint4*)(value + base + r11);
      const fl2 w00v = {w00, w00}, w10v = {w10, w10};
      const fl2 w01v = {w01, w01}, w11v = {w11, w11};
      const uint* u00 = (const uint*)&q00;
      const uint* u10 = (const uint*)&q10;
      const uint* u01 = (const uint*)&q01;
      const uint* u11 = (const uint*)&q11;
#pragma unroll
      for (int pp = 0; pp < 4; pp++) {
        const fl2 v00 = {blo(u00[pp]), bhi(u00[pp])};
        const fl2 v10 = {blo(u10[pp]), bhi(u10[pp])};
        const fl2 v01 = {blo(u01[pp]), bhi(u01[pp])};
        const fl2 v11 = {blo(u11[pp]), bhi(u11[pp])};
        acc2[pp] += w00v * v00 + w10v * v10 + w01v * v01 + w11v * v11;
      }
    }
  }
  ushort4 o0, o1;
  o0.x = f2b(acc2[0].x); o0.y = f2b(acc2[0].y);
  o0.z = f2b(acc2[1].x); o0.w = f2b(acc2[1].y);
  o1.x = f2b(acc2[2].x); o1.y = f2b(acc2[2].y);
  o1.z = f2b(acc2[3].x); o1.w = f2b(acc2[3].y);
  ushort* op = outb + (uint)tok * 256u + (uint)(l * 8);
  *(ushort4*)op = o0;
  *(ushort4*)(op + 4) = o1;
}

// ---------------- LayerNorm over 256 (wave per row, 4 rows/block) -----------
template <int OUTF>
__global__ __launch_bounds__(256) void ln256(
    const ushort* __restrict__ in, const float* __restrict__ gg,
    const float* __restrict__ bb, ushort* __restrict__ outb,
    float* __restrict__ outf, int rows)
{
  const int wave = threadIdx.x >> 6, lane = threadIdx.x & 63;
  const int r = blockIdx.x * 4 + wave;
  if (r >= rows) return;
  const ushort* rowp = in + (size_t)r * 256;
  const ushort4 u = *(const ushort4*)(rowp + lane * 4);
  float v[4] = {b2f(u.x), b2f(u.y), b2f(u.z), b2f(u.w)};
  float s = v[0] + v[1] + v[2] + v[3];
  float s2 = v[0] * v[0] + v[1] * v[1] + v[2] * v[2] + v[3] * v[3];
#pragma unroll
  for (int o = 32; o > 0; o >>= 1) {
    s += __shfl_xor(s, o);
    s2 += __shfl_xor(s2, o);
  }
  const float mean = s * (1.f / 256.f);
  const float var = s2 * (1.f / 256.f) - mean * mean;
  const float rstd = rsqrtf(var + 1e-5f);
#pragma unroll
  for (int j = 0; j < 4; j++) {
    const int col = lane * 4 + j;
    const float o = (v[j] - mean) * rstd * gg[col] + bb[col];
    if (OUTF) outf[(size_t)r * 256 + col] = o;
    else outb[(size_t)r * 256 + col] = f2b(o);
  }
}

// ---------------------------------------------------------------------------
extern "C" void kernel_launch(void* const* d_in, const int* in_sizes, int n_in,
                              void* d_out, int out_size, void* d_ws, size_t ws_size,
                              hipStream_t stream)
{
  const float* src   = (const float*)d_in[0];
  const float* pos   = (const float*)d_in[1];
  const float* refp  = (const float*)d_in[2];
  const float* Wv    = (const float*)d_in[3];
  const float* bv    = (const float*)d_in[4];
  const float* Woff  = (const float*)d_in[5];
  const float* boff  = (const float*)d_in[6];
  const float* Wattn = (const float*)d_in[7];
  const float* battn = (const float*)d_in[8];
  const float* Wout  = (const float*)d_in[9];
  const float* bout  = (const float*)d_in[10];
  const float* g1    = (const float*)d_in[11];
  const float* b1    = (const float*)d_in[12];
  const float* Wff1  = (const float*)d_in[13];
  const float* bff1  = (const float*)d_in[14];
  const float* Wff2  = (const float*)d_in[15];
  const float* bff2  = (const float*)d_in[16];
  const float* g2    = (const float*)d_in[17];
  const float* b2    = (const float*)d_in[18];
  float* out = (float*)d_out;
  char* ws = (char*)d_ws;

  // workspace (bytes). wv_t / wout_t overlaid on A5 tail (dead before G4
  // writes h there); attn_out uses A5's head (dead until G4).
  ushort* wcat_t = (ushort*)(ws + 0);            //   196608 (384 x 256)
  ushort* wff1_t = (ushort*)(ws + 196608);       //   524288
  ushort* wff2_t = (ushort*)(ws + 720896);       //   524288
  float*  bcat   = (float*)(ws + 1245184);       //     1536
  ushort* A1 = (ushort*)(ws + 1246720);          // src_bf (lives to G3)
  ushort* A2 = (ushort*)(ws + 28182016);         // q_bf -> x_bf
  ushort* A3 = (ushort*)(ws + 55117312);         // value -> y_bf
  ushort* A4 = (ushort*)(ws + 81997312);         // offattn(320) -> xpre(256)
  ushort* A5 = (ushort*)(ws + 115597312);        // attn_out (head) -> h (MPx1024)
  ushort* wout_t = (ushort*)(ws + 223076352);    //   131072 (A5 tail)
  ushort* wv_t   = (ushort*)(ws + 223207424);    //   131072 (A5 tail)
  // end: 223338496

  prep_weights<<<2946, 256, 0, stream>>>(Wv, Woff, Wattn, Wout, Wff1, Wff2,
                                         boff, battn,
                                         wv_t, wcat_t, wout_t, wff1_t, wff2_t, bcat);
  prep_act<<<MP / 4, 256, 0, stream>>>(src, pos, A1, A2);
  // G1: value = src @ Wv + bv
  gemm128<0><<<dim3(2, MP / 128), 256, 0, stream>>>(A1, wv_t, bv, nullptr, nullptr,
                                                    A3, BLTOK, 256, 256, 256);
  // G2: offattn = q @ Wcat + bcat  (N=320, tiles to 384)
  gemm128<0><<<dim3(3, MP / 128), 256, 0, stream>>>(A2, wcat_t, bcat, nullptr, nullptr,
                                                    A4, BLTOK, 320, 320, 256);
  // attn_out -> A5 head  (softmax fused in-register)
  deform_sample<<<(BLTOK + 7) / 8, 256, 0, stream>>>(A3, A4, refp, A5);
  // G3: xpre = src_bf + attn_out @ Wout + bout  (bf16 residual from A1)
  gemm128<3><<<dim3(2, MP / 128), 256, 0, stream>>>(A5, wout_t, bout, nullptr, A1,
                                                    A4, BLTOK, 256, 256, 256);
  ln256<0><<<BLTOK / 4, 256, 0, stream>>>(A4, g1, b1, A2, nullptr, BLTOK);
  // G4: h = relu(x @ Wff1 + bff1) — store pad rows too (A2 pads are zero)
  gemm128<2><<<dim3(8, MP / 128), 256, 0, stream>>>(A2, wff1_t, bff1, nullptr, nullptr,
                                                    A5, MP, 1024, 1024, 256);
  // G5: y = x + h @ Wff2 + bff2
  gemm128<3><<<dim3(2, MP / 128), 256, 0, stream>>>(A5, wff2_t, bff2, nullptr, A2,
                                                    A3, BLTOK, 256, 256, 1024);
  ln256<1><<<BLTOK / 4, 256, 0, stream>>>(A3, g2, b2, nullptr, out, BLTOK);
}